// Round 3
// baseline (1344.188 us; speedup 1.0000x reference)
//
#include <hip/hip_runtime.h>
#include <cfloat>
#include <cmath>

#define N_P 50000
#define N_W 10000
#define D_P 256
#define D_W 128
#define HID 64
#define OUTD 8
#define KH 4
#define LL 2
#define E_PP 500000
#define E_PW 150000
#define E_WP 150000

__device__ inline float atomicMaxFloat(float* addr, float value) {
    if (value >= 0.f)
        return __int_as_float(atomicMax((int*)addr, __float_as_int(value)));
    else
        return __uint_as_float(atomicMin((unsigned int*)addr, __float_as_uint(value)));
}

__device__ inline float lrelu02(float v) { return v > 0.f ? v : 0.2f * v; }

// ---------------------------------------------------------------------------
// Tiled register-blocked GEMM: C[M,N] = A[M,K] @ B[K,N] (+bias).
// 256 threads. Each thread: TM rows x 4 cols. A staged transposed in LDS.
// ---------------------------------------------------------------------------
template<int N, int TM>
__global__ __launch_bounds__(256) void gemm_tiled(const float* __restrict__ A,
                                                  const float* __restrict__ B,
                                                  const float* __restrict__ bias,
                                                  float* __restrict__ C,
                                                  int M, int K) {
    constexpr int CG = N / 4;
    constexpr int RG = 256 / CG;
    constexpr int ROWS = RG * TM;
    constexpr int KC = 64;
    __shared__ float As[KC * ROWS];

    int tid = threadIdx.x;
    int cg = tid % CG;
    int rg = tid / CG;
    int r_base = blockIdx.x * ROWS;
    int row0 = rg * TM;

    float acc[TM][4];
#pragma unroll
    for (int m = 0; m < TM; ++m)
#pragma unroll
        for (int j = 0; j < 4; ++j) acc[m][j] = 0.f;

    for (int kc = 0; kc < K; kc += KC) {
        __syncthreads();
        constexpr int LOADS = ROWS * KC / (4 * 256);
#pragma unroll
        for (int it = 0; it < LOADS; ++it) {
            int f4 = it * 256 + tid;
            int i = f4 % ROWS;
            int j4 = f4 / ROWS;
            int grow = r_base + i;
            float4 a4 = make_float4(0.f, 0.f, 0.f, 0.f);
            if (grow < M) a4 = *(const float4*)&A[(size_t)grow * K + kc + j4 * 4];
            As[(j4 * 4 + 0) * ROWS + i] = a4.x;
            As[(j4 * 4 + 1) * ROWS + i] = a4.y;
            As[(j4 * 4 + 2) * ROWS + i] = a4.z;
            As[(j4 * 4 + 3) * ROWS + i] = a4.w;
        }
        __syncthreads();

        const float4* B4 = (const float4*)(B + (size_t)kc * N) + cg;
#pragma unroll
        for (int k = 0; k < KC; ++k) {
            float4 b = B4[(size_t)k * CG];
#pragma unroll
            for (int m4 = 0; m4 < TM / 4; ++m4) {
                float4 a = *(const float4*)&As[k * ROWS + row0 + m4 * 4];
                float av[4] = {a.x, a.y, a.z, a.w};
#pragma unroll
                for (int mm = 0; mm < 4; ++mm) {
                    int m = m4 * 4 + mm;
                    acc[m][0] = fmaf(av[mm], b.x, acc[m][0]);
                    acc[m][1] = fmaf(av[mm], b.y, acc[m][1]);
                    acc[m][2] = fmaf(av[mm], b.z, acc[m][2]);
                    acc[m][3] = fmaf(av[mm], b.w, acc[m][3]);
                }
            }
        }
    }

    float4 bv = make_float4(0.f, 0.f, 0.f, 0.f);
    if (bias) bv = *(const float4*)&bias[cg * 4];
#pragma unroll
    for (int m = 0; m < TM; ++m) {
        int grow = r_base + row0 + m;
        if (grow < M) {
            float4 o;
            o.x = acc[m][0] + bv.x;
            o.y = acc[m][1] + bv.y;
            o.z = acc[m][2] + bv.z;
            o.w = acc[m][3] + bv.w;
            *(float4*)&C[(size_t)grow * N + cg * 4] = o;
        }
    }
}

// Small-N GEMM: out[n, 0:NC] = h[n, 0:64] @ W[64, NC] (+bias). 1 thread/node.
template<int NC>
__global__ void av_kernel(const float* __restrict__ h, const float* __restrict__ W,
                          const float* __restrict__ bias, float* __restrict__ out, int M) {
    int n = blockIdx.x * blockDim.x + threadIdx.x;
    if (n >= M) return;
    const float4* h4 = (const float4*)(h + (size_t)n * HID);
    float acc[NC];
#pragma unroll
    for (int c = 0; c < NC; ++c) acc[c] = bias ? bias[c] : 0.f;
#pragma unroll
    for (int k4 = 0; k4 < HID / 4; ++k4) {
        float4 hv = h4[k4];
#pragma unroll
        for (int c = 0; c < NC; ++c) {
            acc[c] = fmaf(hv.x, W[(k4 * 4 + 0) * NC + c], acc[c]);
            acc[c] = fmaf(hv.y, W[(k4 * 4 + 1) * NC + c], acc[c]);
            acc[c] = fmaf(hv.z, W[(k4 * 4 + 2) * NC + c], acc[c]);
            acc[c] = fmaf(hv.w, W[(k4 * 4 + 3) * NC + c], acc[c]);
        }
    }
#pragma unroll
    for (int c4 = 0; c4 < NC / 4; ++c4) {
        float4 o = make_float4(acc[c4 * 4 + 0], acc[c4 * 4 + 1], acc[c4 * 4 + 2], acc[c4 * 4 + 3]);
        *(float4*)&out[(size_t)n * NC + c4 * 4] = o;
    }
}

// wv[lt][j,k] = sum_h W[lt][j, k*64+h] * att[lt][k,h].
__global__ void wv_kernel(const float* __restrict__ W, const float* __restrict__ att,
                          float* __restrict__ wv) {
    int lt = blockIdx.x;
    int j = threadIdx.x >> 2, k = threadIdx.x & 3;
    const float* Wp = W + (size_t)lt * HID * (KH * HID) + (size_t)j * (KH * HID) + k * HID;
    const float* ap = att + (size_t)lt * KH * HID + k * HID;
    float s = 0.f;
    for (int h = 0; h < HID; ++h) s += Wp[h] * ap[h];
    wv[(size_t)lt * HID * KH + j * KH + k] = s;
}

__global__ void init_out_kernel(float* __restrict__ o, const float* __restrict__ b1,
                                const float* __restrict__ b2, int total) {
    int i = blockIdx.x * blockDim.x + threadIdx.x;
    if (i >= total) return;
    int h = i & (HID - 1);
    o[i] = b1[h] + (b2 ? b2[h] : 0.f);
}

__global__ void reset_md_kernel(float* __restrict__ m, float* __restrict__ den, int n) {
    int i = blockIdx.x * blockDim.x + threadIdx.x;
    if (i < n) { m[i] = -FLT_MAX; den[i] = 0.f; }
}

// E threads; per-edge float4 logit -> atomicMax into m[dst]
__global__ void edge_max_v2(const int* __restrict__ src, const int* __restrict__ dst,
                            const float4* __restrict__ a_s, const float4* __restrict__ a_d,
                            float* __restrict__ m, int E) {
    int e = blockIdx.x * blockDim.x + threadIdx.x;
    if (e >= E) return;
    int s = src[e], d = dst[e];
    float4 as = a_s[s], ad = a_d[d];
    atomicMaxFloat(&m[d * KH + 0], lrelu02(as.x + ad.x));
    atomicMaxFloat(&m[d * KH + 1], lrelu02(as.y + ad.y));
    atomicMaxFloat(&m[d * KH + 2], lrelu02(as.z + ad.z));
    atomicMaxFloat(&m[d * KH + 3], lrelu02(as.w + ad.w));
}

// E threads; t = exp(v - m[dst]); store t to alpha[e]; den[dst] += t
__global__ void edge_sum_v2(const int* __restrict__ src, const int* __restrict__ dst,
                            const float4* __restrict__ a_s, const float4* __restrict__ a_d,
                            const float4* __restrict__ m, float* __restrict__ den,
                            float4* __restrict__ alpha, int E) {
    int e = blockIdx.x * blockDim.x + threadIdx.x;
    if (e >= E) return;
    int s = src[e], d = dst[e];
    float4 as = a_s[s], ad = a_d[d], mm = m[d];
    float4 t;
    t.x = expf(lrelu02(as.x + ad.x) - mm.x);
    t.y = expf(lrelu02(as.y + ad.y) - mm.y);
    t.z = expf(lrelu02(as.z + ad.z) - mm.z);
    t.w = expf(lrelu02(as.w + ad.w) - mm.w);
    alpha[e] = t;
    atomicAdd(&den[d * KH + 0], t.x);
    atomicAdd(&den[d * KH + 1], t.y);
    atomicAdd(&den[d * KH + 2], t.z);
    atomicAdd(&den[d * KH + 3], t.w);
}

// E threads; alpha[e] = 0.25 * alpha[e] / den[dst]  (head-mean folded in)
__global__ void alpha_div_kernel(const int* __restrict__ dst, const float4* __restrict__ den,
                                 float4* __restrict__ alpha, int E) {
    int e = blockIdx.x * blockDim.x + threadIdx.x;
    if (e >= E) return;
    float4 t = alpha[e];
    float4 dn = den[dst[e]];
    t.x = 0.25f * t.x / dn.x;
    t.y = 0.25f * t.y / dn.y;
    t.z = 0.25f * t.z / dn.z;
    t.w = 0.25f * t.w / dn.w;
    alpha[e] = t;
}

// one 64-lane wave per edge; lane = feature h. Pure gather + fma + atomic.
__global__ void edge_msg_v2(const int* __restrict__ src, const int* __restrict__ dst,
                            const float4* __restrict__ alpha,
                            const float* __restrict__ hs, float* __restrict__ o, int E) {
    int gid = blockIdx.x * blockDim.x + threadIdx.x;
    int e = gid >> 6;
    int h = gid & 63;
    if (e >= E) return;
    int s = src[e], d = dst[e];
    float4 al = alpha[e];
    const float* hp = hs + (size_t)s * (KH * HID) + h;
    float acc;
    acc = al.x * hp[0];
    acc = fmaf(al.y, hp[HID], acc);
    acc = fmaf(al.z, hp[2 * HID], acc);
    acc = fmaf(al.w, hp[3 * HID], acc);
    atomicAdd(&o[(size_t)d * HID + h], acc);
}

__global__ void elu_update_kernel(const float* __restrict__ o, float* __restrict__ h,
                                  float scale, int n) {
    int i = blockIdx.x * blockDim.x + threadIdx.x;
    if (i < n) {
        float x = scale * o[i];
        h[i] = x > 0.f ? x : expf(x) - 1.f;
    }
}

extern "C" void kernel_launch(void* const* d_in, const int* in_sizes, int n_in,
                              void* d_out, int out_size, void* d_ws, size_t ws_size,
                              hipStream_t stream) {
    const float* x_p    = (const float*)d_in[0];
    const float* x_w    = (const float*)d_in[1];
    const float* Wpp    = (const float*)d_in[2];
    const float* bpp    = (const float*)d_in[3];
    const float* Wpw    = (const float*)d_in[4];
    const float* bpw    = (const float*)d_in[5];
    const float* Wsrc   = (const float*)d_in[6];   // (2,3,64,256)
    const float* Wdst   = (const float*)d_in[7];   // (2,3,64,256)
    const float* Asrc   = (const float*)d_in[8];   // (2,3,4,64)
    const float* Adst   = (const float*)d_in[9];   // (2,3,4,64)
    const float* cbias  = (const float*)d_in[10];  // (2,3,64)
    const float* Wpostp = (const float*)d_in[11];
    const float* bpostp = (const float*)d_in[12];
    const float* Wpostw = (const float*)d_in[13];
    const float* bpostw = (const float*)d_in[14];
    const int*   ei_pp  = (const int*)d_in[15];    // (2, E_PP): src then dst
    const int*   ei_pw  = (const int*)d_in[16];
    const int*   ei_wp  = (const int*)d_in[17];

    float* ws = (float*)d_ws;
    float* h_p   = ws; ws += (size_t)N_P * HID;
    float* h_w   = ws; ws += (size_t)N_W * HID;
    float* o_p   = ws; ws += (size_t)N_P * HID;
    float* o_w   = ws; ws += (size_t)N_W * HID;
    float* hs    = ws; ws += (size_t)N_P * KH * HID;
    float* a_s   = ws; ws += (size_t)N_P * KH;
    float* a_d   = ws; ws += (size_t)N_P * KH;
    float* mbuf  = ws; ws += (size_t)N_P * KH;
    float* den   = ws; ws += (size_t)N_P * KH;
    float* alpha = ws; ws += (size_t)E_PP * KH;
    float* wv_s  = ws; ws += (size_t)LL * 3 * HID * KH;
    float* wv_d  = ws; ws += (size_t)LL * 3 * HID * KH;

    auto cdiv = [](long long a, long long b) { return (int)((a + b - 1) / b); };

    wv_kernel<<<LL * 3, 256, 0, stream>>>(Wsrc, Asrc, wv_s);
    wv_kernel<<<LL * 3, 256, 0, stream>>>(Wdst, Adst, wv_d);

    gemm_tiled<64, 8><<<cdiv(N_P, 128), 256, 0, stream>>>(x_p, Wpp, bpp, h_p, N_P, D_P);
    gemm_tiled<64, 8><<<cdiv(N_W, 128), 256, 0, stream>>>(x_w, Wpw, bpw, h_w, N_W, D_W);

    for (int l = 0; l < LL; ++l) {
        init_out_kernel<<<cdiv((long long)N_P * HID, 256), 256, 0, stream>>>(
            o_p, cbias + (l * 3 + 0) * HID, cbias + (l * 3 + 2) * HID, N_P * HID);
        init_out_kernel<<<cdiv((long long)N_W * HID, 256), 256, 0, stream>>>(
            o_w, cbias + (l * 3 + 1) * HID, nullptr, N_W * HID);

        struct GatDesc { const float* hsrc; const float* hdst; int Ns, Nd, E; const int* ei; float* out; };
        GatDesc gats[3] = {
            { h_p, h_p, N_P, N_P, E_PP, ei_pp, o_p },
            { h_p, h_w, N_P, N_W, E_PW, ei_pw, o_w },
            { h_w, h_p, N_W, N_P, E_WP, ei_wp, o_p },
        };
        for (int t = 0; t < 3; ++t) {
            int lt = l * 3 + t;
            GatDesc& g = gats[t];
            const float* Ws = Wsrc + (size_t)lt * HID * KH * HID;
            gemm_tiled<256, 8><<<cdiv(g.Ns, 32), 256, 0, stream>>>(g.hsrc, Ws, nullptr, hs, g.Ns, HID);
            av_kernel<4><<<cdiv(g.Ns, 256), 256, 0, stream>>>(
                g.hsrc, wv_s + (size_t)lt * HID * KH, nullptr, a_s, g.Ns);
            av_kernel<4><<<cdiv(g.Nd, 256), 256, 0, stream>>>(
                g.hdst, wv_d + (size_t)lt * HID * KH, nullptr, a_d, g.Nd);
            reset_md_kernel<<<cdiv((long long)g.Nd * KH, 256), 256, 0, stream>>>(mbuf, den, g.Nd * KH);
            const int* src = g.ei;
            const int* dst = g.ei + g.E;
            edge_max_v2<<<cdiv(g.E, 256), 256, 0, stream>>>(
                src, dst, (const float4*)a_s, (const float4*)a_d, mbuf, g.E);
            edge_sum_v2<<<cdiv(g.E, 256), 256, 0, stream>>>(
                src, dst, (const float4*)a_s, (const float4*)a_d, (const float4*)mbuf,
                den, (float4*)alpha, g.E);
            alpha_div_kernel<<<cdiv(g.E, 256), 256, 0, stream>>>(
                dst, (const float4*)den, (float4*)alpha, g.E);
            edge_msg_v2<<<cdiv((long long)g.E * 64, 256), 256, 0, stream>>>(
                src, dst, (const float4*)alpha, hs, g.out, g.E);
        }
        elu_update_kernel<<<cdiv((long long)N_P * HID, 256), 256, 0, stream>>>(o_p, h_p, 0.5f, N_P * HID);
        elu_update_kernel<<<cdiv((long long)N_W * HID, 256), 256, 0, stream>>>(o_w, h_w, 1.0f, N_W * HID);
    }

    float* out_p = (float*)d_out;
    float* out_w = out_p + (size_t)N_P * OUTD;
    av_kernel<8><<<cdiv(N_P, 256), 256, 0, stream>>>(h_p, Wpostp, bpostp, out_p, N_P);
    av_kernel<8><<<cdiv(N_W, 256), 256, 0, stream>>>(h_w, Wpostw, bpostw, out_w, N_W);
}

// Round 5
// 780.028 us; speedup vs baseline: 1.7233x; 1.7233x over previous
//
#include <hip/hip_runtime.h>
#include <hip/hip_fp16.h>
#include <cfloat>
#include <cmath>

#define N_P 50000
#define N_W 10000
#define D_P 256
#define D_W 128
#define HID 64
#define OUTD 8
#define KH 4
#define LL 2
#define E_PP 500000
#define E_PW 150000
#define E_WP 150000

__device__ inline float lrelu02(float v) { return v > 0.f ? v : 0.2f * v; }

__device__ inline float4 ld4(const float* p) { return *(const float4*)p; }
__device__ inline float4 ld4(const __half* p) {
    const __half2* q = (const __half2*)p;
    __half2 a = q[0], b = q[1];
    return make_float4(__half2float(a.x), __half2float(a.y),
                       __half2float(b.x), __half2float(b.y));
}

// ---------------------------------------------------------------------------
// GEMM: C[M,64] = A[M,K] @ B[K,64] (+bias, opt ELU). Also mirrors C to fp16.
// 256 threads, 8 rows x 4 cols per thread, A staged transposed in LDS.
// ---------------------------------------------------------------------------
template<typename AT>
__global__ __launch_bounds__(256) void gemm64(const AT* __restrict__ A,
                                              const float* __restrict__ B,
                                              const float* __restrict__ bias,
                                              float* __restrict__ C,
                                              __half* __restrict__ C16,
                                              int M, int K, int applyElu) {
    constexpr int N = 64, TM = 8;
    constexpr int CG = N / 4;       // 16
    constexpr int RG = 256 / CG;    // 16
    constexpr int ROWS = RG * TM;   // 128
    constexpr int KC = 64;
    __shared__ float As[KC * ROWS];

    int tid = threadIdx.x;
    int cg = tid % CG;
    int rg = tid / CG;
    int r_base = blockIdx.x * ROWS;
    int row0 = rg * TM;

    float acc[TM][4];
#pragma unroll
    for (int m = 0; m < TM; ++m)
#pragma unroll
        for (int j = 0; j < 4; ++j) acc[m][j] = 0.f;

    for (int kc = 0; kc < K; kc += KC) {
        __syncthreads();
        constexpr int LOADS = ROWS * KC / (4 * 256);  // 8
#pragma unroll
        for (int it = 0; it < LOADS; ++it) {
            int f4 = it * 256 + tid;
            int i = f4 % ROWS;
            int j4 = f4 / ROWS;
            int grow = r_base + i;
            float4 a4 = make_float4(0.f, 0.f, 0.f, 0.f);
            if (grow < M) a4 = ld4(&A[(size_t)grow * K + kc + j4 * 4]);
            As[(j4 * 4 + 0) * ROWS + i] = a4.x;
            As[(j4 * 4 + 1) * ROWS + i] = a4.y;
            As[(j4 * 4 + 2) * ROWS + i] = a4.z;
            As[(j4 * 4 + 3) * ROWS + i] = a4.w;
        }
        __syncthreads();

        const float4* B4 = (const float4*)(B + (size_t)kc * N) + cg;
#pragma unroll
        for (int k = 0; k < KC; ++k) {
            float4 b = B4[(size_t)k * CG];
#pragma unroll
            for (int m4 = 0; m4 < TM / 4; ++m4) {
                float4 a = *(const float4*)&As[k * ROWS + row0 + m4 * 4];
                float av[4] = {a.x, a.y, a.z, a.w};
#pragma unroll
                for (int mm = 0; mm < 4; ++mm) {
                    int m = m4 * 4 + mm;
                    acc[m][0] = fmaf(av[mm], b.x, acc[m][0]);
                    acc[m][1] = fmaf(av[mm], b.y, acc[m][1]);
                    acc[m][2] = fmaf(av[mm], b.z, acc[m][2]);
                    acc[m][3] = fmaf(av[mm], b.w, acc[m][3]);
                }
            }
        }
    }

    float4 bv = make_float4(0.f, 0.f, 0.f, 0.f);
    if (bias) bv = *(const float4*)&bias[cg * 4];
#pragma unroll
    for (int m = 0; m < TM; ++m) {
        int grow = r_base + row0 + m;
        if (grow < M) {
            float4 o;
            o.x = acc[m][0] + bv.x;
            o.y = acc[m][1] + bv.y;
            o.z = acc[m][2] + bv.z;
            o.w = acc[m][3] + bv.w;
            if (applyElu) {
                o.x = o.x > 0.f ? o.x : expf(o.x) - 1.f;
                o.y = o.y > 0.f ? o.y : expf(o.y) - 1.f;
                o.z = o.z > 0.f ? o.z : expf(o.z) - 1.f;
                o.w = o.w > 0.f ? o.w : expf(o.w) - 1.f;
            }
            size_t idx = (size_t)grow * N + cg * 4;
            *(float4*)&C[idx] = o;
            if (C16) {
                __half2 h01 = __floats2half2_rn(o.x, o.y);
                __half2 h23 = __floats2half2_rn(o.z, o.w);
                *(__half2*)&C16[idx] = h01;
                *(__half2*)&C16[idx + 2] = h23;
            }
        }
    }
}

// Small-N GEMM: out[n, 0:NC] = h[n, 0:64] @ W[64, NC] (+bias). 1 thread/node.
template<int NC>
__global__ void av_kernel(const float* __restrict__ h, const float* __restrict__ W,
                          const float* __restrict__ bias, float* __restrict__ out, int M) {
    int n = blockIdx.x * blockDim.x + threadIdx.x;
    if (n >= M) return;
    const float4* h4 = (const float4*)(h + (size_t)n * HID);
    float acc[NC];
#pragma unroll
    for (int c = 0; c < NC; ++c) acc[c] = bias ? bias[c] : 0.f;
#pragma unroll
    for (int k4 = 0; k4 < HID / 4; ++k4) {
        float4 hv = h4[k4];
#pragma unroll
        for (int c = 0; c < NC; ++c) {
            acc[c] = fmaf(hv.x, W[(k4 * 4 + 0) * NC + c], acc[c]);
            acc[c] = fmaf(hv.y, W[(k4 * 4 + 1) * NC + c], acc[c]);
            acc[c] = fmaf(hv.z, W[(k4 * 4 + 2) * NC + c], acc[c]);
            acc[c] = fmaf(hv.w, W[(k4 * 4 + 3) * NC + c], acc[c]);
        }
    }
#pragma unroll
    for (int c4 = 0; c4 < NC / 4; ++c4) {
        float4 o = make_float4(acc[c4 * 4 + 0], acc[c4 * 4 + 1],
                               acc[c4 * 4 + 2], acc[c4 * 4 + 3]);
        *(float4*)&out[(size_t)n * NC + c4 * 4] = o;
    }
}

// wv[lt][j,k] = sum_h W[lt][j, k*64+h] * att[lt][k,h].
__global__ void wv_kernel(const float* __restrict__ W, const float* __restrict__ att,
                          float* __restrict__ wv) {
    int lt = blockIdx.x;
    int j = threadIdx.x >> 2, k = threadIdx.x & 3;
    const float* Wp = W + (size_t)lt * HID * (KH * HID) + (size_t)j * (KH * HID) + k * HID;
    const float* ap = att + (size_t)lt * KH * HID + k * HID;
    float s = 0.f;
    for (int h = 0; h < HID; ++h) s += Wp[h] * ap[h];
    wv[(size_t)lt * HID * KH + j * KH + k] = s;
}

// Wcomb for the post-aggregation GEMMs; scales fold head-mean and hetero-mean.
// NOTE: alpha from gat_agg is a PLAIN softmax (sums to 1 per head); the 1/4
// head-mean and 1/2 hetero-mean live ONLY here (0.125 = 0.25*0.5, 0.25).
__global__ void build_wcomb(const float* __restrict__ Wsrc, const float* __restrict__ cbias,
                            int l, float* __restrict__ wcp, float* __restrict__ bp,
                            float* __restrict__ wcw, float* __restrict__ bw) {
    int t = blockIdx.x * blockDim.x + threadIdx.x;
    if (t < 512 * 64) {
        int row = t >> 6, h = t & 63;
        int part = row >> 8;          // 0: pp (type0), 1: wp (type2)
        int r = row & 255;
        int k = r >> 6, j = r & 63;
        int type = (part == 0) ? 0 : 2;
        wcp[t] = Wsrc[(((size_t)l * 3 + type) * 64 + j) * 256 + k * 64 + h] * 0.125f;
    } else if (t < 512 * 64 + 256 * 64) {
        int u = t - 512 * 64;
        int row = u >> 6, h = u & 63;
        int k = row >> 6, j = row & 63;
        wcw[u] = Wsrc[(((size_t)l * 3 + 1) * 64 + j) * 256 + k * 64 + h] * 0.25f;
    }
    if (t < 64) bp[t] = 0.5f * (cbias[(l * 3 + 0) * 64 + t] + cbias[(l * 3 + 2) * 64 + t]);
    else if (t >= 64 && t < 128) bw[t - 64] = cbias[(l * 3 + 1) * 64 + (t - 64)];
}

// ---------------- CSR build ----------------
__global__ void count_kernel(const int* __restrict__ dst, int* __restrict__ cnt, int E) {
    int e = blockIdx.x * blockDim.x + threadIdx.x;
    if (e < E) atomicAdd(&cnt[dst[e]], 1);
}

// single block, 1024 threads; exclusive scan cw[0..n) -> rowptr[0..n], cw:=excl (woff)
__global__ __launch_bounds__(1024) void scan_kernel(int* __restrict__ cw,
                                                    int* __restrict__ rowptr, int n) {
    __shared__ int wsum[16];
    __shared__ int wexc[16];
    __shared__ int carry_s;
    int tid = threadIdx.x;
    int lane = tid & 63, wv = tid >> 6;
    if (tid == 0) carry_s = 0;
    __syncthreads();
    for (int base = 0; base < n; base += 1024) {
        int i = base + tid;
        int v = (i < n) ? cw[i] : 0;
        int x = v;
#pragma unroll
        for (int off = 1; off < 64; off <<= 1) {
            int y = __shfl_up(x, off, 64);
            if (lane >= off) x += y;
        }
        if (lane == 63) wsum[wv] = x;
        __syncthreads();
        if (wv == 0 && lane < 16) {
            int s = wsum[lane];
            int xx = s;
#pragma unroll
            for (int off = 1; off < 16; off <<= 1) {
                int y = __shfl_up(xx, off, 64);
                if (lane >= off) xx += y;
            }
            wexc[lane] = xx - s;
            if (lane == 15) wsum[15] = xx;   // chunk total
        }
        __syncthreads();
        int excl = x - v + wexc[wv] + carry_s;
        if (i < n) { rowptr[i] = excl; cw[i] = excl; }
        if (i == n - 1) rowptr[n] = excl + v;
        int ctot = wsum[15];
        __syncthreads();
        if (tid == 0) carry_s += ctot;
        __syncthreads();
    }
}

__global__ void scatter_kernel(const int* __restrict__ src, const int* __restrict__ dst,
                               int* __restrict__ woff, int* __restrict__ perm, int E) {
    int e = blockIdx.x * blockDim.x + threadIdx.x;
    if (e < E) {
        int p = atomicAdd(&woff[dst[e]], 1);
        perm[p] = src[e];
    }
}

// ---------------------------------------------------------------------------
// Fused GAT aggregation: one wave per destination node.
// agg[d, col_off + k*64 + h] = sum_e alpha[e,k] * h16[src_e, h]   (fp16 out)
// alpha is plain softmax over the dst neighborhood (no extra scaling here).
// ---------------------------------------------------------------------------
__global__ __launch_bounds__(256) void gat_agg_kernel(
    const int* __restrict__ rowptr, const int* __restrict__ perm_src,
    const float4* __restrict__ a_s, const float4* __restrict__ a_d,
    const __half* __restrict__ h16, __half* __restrict__ agg,
    int ldagg, int col_off, int n_dst) {
    __shared__ float4 s_al[4][64];
    __shared__ int s_sr[4][64];
    int lane = threadIdx.x & 63;
    int wv = threadIdx.x >> 6;
    int d = (blockIdx.x << 2) + wv;
    if (d >= n_dst) return;
    int base = rowptr[d];
    int len = rowptr[d + 1] - base;
    float4 ad = a_d[d];

    float4 mx = make_float4(-FLT_MAX, -FLT_MAX, -FLT_MAX, -FLT_MAX);
    for (int i = lane; i < len; i += 64) {
        int s = perm_src[base + i];
        float4 as = a_s[s];
        mx.x = fmaxf(mx.x, lrelu02(as.x + ad.x));
        mx.y = fmaxf(mx.y, lrelu02(as.y + ad.y));
        mx.z = fmaxf(mx.z, lrelu02(as.z + ad.z));
        mx.w = fmaxf(mx.w, lrelu02(as.w + ad.w));
    }
#pragma unroll
    for (int off = 32; off > 0; off >>= 1) {
        mx.x = fmaxf(mx.x, __shfl_xor(mx.x, off, 64));
        mx.y = fmaxf(mx.y, __shfl_xor(mx.y, off, 64));
        mx.z = fmaxf(mx.z, __shfl_xor(mx.z, off, 64));
        mx.w = fmaxf(mx.w, __shfl_xor(mx.w, off, 64));
    }

    float4 sm = make_float4(0.f, 0.f, 0.f, 0.f);
    for (int i = lane; i < len; i += 64) {
        int s = perm_src[base + i];
        float4 as = a_s[s];
        sm.x += expf(lrelu02(as.x + ad.x) - mx.x);
        sm.y += expf(lrelu02(as.y + ad.y) - mx.y);
        sm.z += expf(lrelu02(as.z + ad.z) - mx.z);
        sm.w += expf(lrelu02(as.w + ad.w) - mx.w);
    }
#pragma unroll
    for (int off = 32; off > 0; off >>= 1) {
        sm.x += __shfl_xor(sm.x, off, 64);
        sm.y += __shfl_xor(sm.y, off, 64);
        sm.z += __shfl_xor(sm.z, off, 64);
        sm.w += __shfl_xor(sm.w, off, 64);
    }
    float4 inv;
    inv.x = len ? 1.0f / sm.x : 0.f;
    inv.y = len ? 1.0f / sm.y : 0.f;
    inv.z = len ? 1.0f / sm.z : 0.f;
    inv.w = len ? 1.0f / sm.w : 0.f;

    float a0 = 0.f, a1 = 0.f, a2 = 0.f, a3 = 0.f;
    for (int c0 = 0; c0 < len; c0 += 64) {
        int i = c0 + lane;
        if (i < len) {
            int s = perm_src[base + i];
            float4 as = a_s[s];
            float4 al;
            al.x = expf(lrelu02(as.x + ad.x) - mx.x) * inv.x;
            al.y = expf(lrelu02(as.y + ad.y) - mx.y) * inv.y;
            al.z = expf(lrelu02(as.z + ad.z) - mx.z) * inv.z;
            al.w = expf(lrelu02(as.w + ad.w) - mx.w) * inv.w;
            s_al[wv][lane] = al;
            s_sr[wv][lane] = s;
        }
        int cnt = min(64, len - c0);
        for (int j = 0; j < cnt; ++j) {
            int sj = s_sr[wv][j];
            float4 al = s_al[wv][j];
            float hv = __half2float(h16[(size_t)sj * HID + lane]);
            a0 = fmaf(al.x, hv, a0);
            a1 = fmaf(al.y, hv, a1);
            a2 = fmaf(al.z, hv, a2);
            a3 = fmaf(al.w, hv, a3);
        }
    }
    size_t ob = (size_t)d * ldagg + col_off + lane;
    agg[ob]       = __float2half(a0);
    agg[ob + 64]  = __float2half(a1);
    agg[ob + 128] = __float2half(a2);
    agg[ob + 192] = __float2half(a3);
}

extern "C" void kernel_launch(void* const* d_in, const int* in_sizes, int n_in,
                              void* d_out, int out_size, void* d_ws, size_t ws_size,
                              hipStream_t stream) {
    const float* x_p    = (const float*)d_in[0];
    const float* x_w    = (const float*)d_in[1];
    const float* Wpp    = (const float*)d_in[2];
    const float* bpp    = (const float*)d_in[3];
    const float* Wpw    = (const float*)d_in[4];
    const float* bpw    = (const float*)d_in[5];
    const float* Wsrc   = (const float*)d_in[6];   // (2,3,64,256)
    const float* Wdst   = (const float*)d_in[7];   // (2,3,64,256)
    const float* Asrc   = (const float*)d_in[8];   // (2,3,4,64)
    const float* Adst   = (const float*)d_in[9];   // (2,3,4,64)
    const float* cbias  = (const float*)d_in[10];  // (2,3,64)
    const float* Wpostp = (const float*)d_in[11];
    const float* bpostp = (const float*)d_in[12];
    const float* Wpostw = (const float*)d_in[13];
    const float* bpostw = (const float*)d_in[14];
    const int*   ei_pp  = (const int*)d_in[15];    // (2,E): src row then dst row
    const int*   ei_pw  = (const int*)d_in[16];
    const int*   ei_wp  = (const int*)d_in[17];

    char* base = (char*)d_ws;
    size_t off = 0;
    auto alloc = [&](size_t bytes) -> void* {
        void* p = base + off;
        off = (off + bytes + 15) & ~(size_t)15;
        return p;
    };

    float*  h_p   = (float*)alloc((size_t)N_P * HID * 4);
    float*  h_w   = (float*)alloc((size_t)N_W * HID * 4);
    __half* h16_p = (__half*)alloc((size_t)N_P * HID * 2);
    __half* h16_w = (__half*)alloc((size_t)N_W * HID * 2);
    float*  a_s   = (float*)alloc((size_t)N_P * KH * 4);
    float*  a_d   = (float*)alloc((size_t)N_P * KH * 4);
    __half* agg_p = (__half*)alloc((size_t)N_P * 512 * 2);
    __half* agg_w = (__half*)alloc((size_t)N_W * 256 * 2);
    float*  wv_s  = (float*)alloc((size_t)LL * 3 * HID * KH * 4);
    float*  wv_d  = (float*)alloc((size_t)LL * 3 * HID * KH * 4);
    float*  wcp   = (float*)alloc(512 * 64 * 4);
    float*  wcw   = (float*)alloc(256 * 64 * 4);
    float*  bp    = (float*)alloc(64 * 4);
    float*  bw    = (float*)alloc(64 * 4);
    int*    rp_pp = (int*)alloc((N_P + 1) * 4);
    int*    cw_pp = (int*)alloc(N_P * 4);
    int*    rp_pw = (int*)alloc((N_W + 1) * 4);
    int*    cw_pw = (int*)alloc(N_W * 4);
    int*    rp_wp = (int*)alloc((N_P + 1) * 4);
    int*    cw_wp = (int*)alloc(N_P * 4);
    int*    pm_pp = (int*)alloc((size_t)E_PP * 4);
    int*    pm_pw = (int*)alloc((size_t)E_PW * 4);
    int*    pm_wp = (int*)alloc((size_t)E_WP * 4);

    auto cdiv = [](long long a, long long b) { return (int)((a + b - 1) / b); };

    // attention weight vectors
    wv_kernel<<<LL * 3, 256, 0, stream>>>(Wsrc, Asrc, wv_s);
    wv_kernel<<<LL * 3, 256, 0, stream>>>(Wdst, Adst, wv_d);

    // CSR build (edges identical across layers)
    struct CsrDesc { const int* ei; int E, n_dst; int *rp, *cw, *pm; };
    CsrDesc csr[3] = {
        { ei_pp, E_PP, N_P, rp_pp, cw_pp, pm_pp },
        { ei_pw, E_PW, N_W, rp_pw, cw_pw, pm_pw },
        { ei_wp, E_WP, N_P, rp_wp, cw_wp, pm_wp },
    };
    for (int t = 0; t < 3; ++t) {
        const int* src = csr[t].ei;
        const int* dst = csr[t].ei + csr[t].E;
        hipMemsetAsync(csr[t].cw, 0, (size_t)csr[t].n_dst * 4, stream);
        count_kernel<<<cdiv(csr[t].E, 256), 256, 0, stream>>>(dst, csr[t].cw, csr[t].E);
        scan_kernel<<<1, 1024, 0, stream>>>(csr[t].cw, csr[t].rp, csr[t].n_dst);
        scatter_kernel<<<cdiv(csr[t].E, 256), 256, 0, stream>>>(src, dst, csr[t].cw, csr[t].pm, csr[t].E);
    }

    // input projections (fp32 h + fp16 mirror)
    gemm64<float><<<cdiv(N_P, 128), 256, 0, stream>>>(x_p, Wpp, bpp, h_p, h16_p, N_P, D_P, 0);
    gemm64<float><<<cdiv(N_W, 128), 256, 0, stream>>>(x_w, Wpw, bpw, h_w, h16_w, N_W, D_W, 0);

    for (int l = 0; l < LL; ++l) {
        build_wcomb<<<cdiv(512 * 64 + 256 * 64, 256), 256, 0, stream>>>(
            Wsrc, cbias, l, wcp, bp, wcw, bw);

        // pp: src=p, dst=p -> agg_p cols [0,256)
        int lt = l * 3 + 0;
        av_kernel<4><<<cdiv(N_P, 256), 256, 0, stream>>>(h_p, wv_s + (size_t)lt * 256, nullptr, a_s, N_P);
        av_kernel<4><<<cdiv(N_P, 256), 256, 0, stream>>>(h_p, wv_d + (size_t)lt * 256, nullptr, a_d, N_P);
        gat_agg_kernel<<<cdiv(N_P, 4), 256, 0, stream>>>(
            rp_pp, pm_pp, (const float4*)a_s, (const float4*)a_d, h16_p, agg_p, 512, 0, N_P);

        // pw: src=p, dst=w -> agg_w cols [0,256)
        lt = l * 3 + 1;
        av_kernel<4><<<cdiv(N_P, 256), 256, 0, stream>>>(h_p, wv_s + (size_t)lt * 256, nullptr, a_s, N_P);
        av_kernel<4><<<cdiv(N_W, 256), 256, 0, stream>>>(h_w, wv_d + (size_t)lt * 256, nullptr, a_d, N_W);
        gat_agg_kernel<<<cdiv(N_W, 4), 256, 0, stream>>>(
            rp_pw, pm_pw, (const float4*)a_s, (const float4*)a_d, h16_p, agg_w, 256, 0, N_W);

        // wp: src=w, dst=p -> agg_p cols [256,512)
        lt = l * 3 + 2;
        av_kernel<4><<<cdiv(N_W, 256), 256, 0, stream>>>(h_w, wv_s + (size_t)lt * 256, nullptr, a_s, N_W);
        av_kernel<4><<<cdiv(N_P, 256), 256, 0, stream>>>(h_p, wv_d + (size_t)lt * 256, nullptr, a_d, N_P);
        gat_agg_kernel<<<cdiv(N_P, 4), 256, 0, stream>>>(
            rp_wp, pm_wp, (const float4*)a_s, (const float4*)a_d, h16_w, agg_p, 512, 256, N_P);

        // post-aggregation projections with fused bias + ELU
        gemm64<__half><<<cdiv(N_P, 128), 256, 0, stream>>>(agg_p, wcp, bp, h_p, h16_p, N_P, 512, 1);
        gemm64<__half><<<cdiv(N_W, 128), 256, 0, stream>>>(agg_w, wcw, bw, h_w, h16_w, N_W, 256, 1);
    }

    float* out_p = (float*)d_out;
    float* out_w = out_p + (size_t)N_P * OUTD;
    av_kernel<8><<<cdiv(N_P, 256), 256, 0, stream>>>(h_p, Wpostp, bpostp, out_p, N_P);
    av_kernel<8><<<cdiv(N_W, 256), 256, 0, stream>>>(h_w, Wpostw, bpostw, out_w, N_W);
}

// Round 6
// 706.351 us; speedup vs baseline: 1.9030x; 1.1043x over previous
//
#include <hip/hip_runtime.h>
#include <hip/hip_fp16.h>
#include <cfloat>
#include <cmath>

#define N_P 50000
#define N_W 10000
#define D_P 256
#define D_W 128
#define HID 64
#define OUTD 8
#define KH 4
#define LL 2
#define E_PP 500000
#define E_PW 150000
#define E_WP 150000

typedef _Float16 f16x8 __attribute__((ext_vector_type(8)));
typedef float f32x4 __attribute__((ext_vector_type(4)));

__device__ inline float lrelu02(float v) { return v > 0.f ? v : 0.2f * v; }

__device__ inline float4 ld4(const float* p) { return *(const float4*)p; }

// ---------------------------------------------------------------------------
// fp32 tiled GEMM for the input projections: C[M,64] = A[M,K] @ B[K,64] + bias.
// 256 threads, TM rows x 4 cols per thread, A staged transposed in LDS.
// TM=4 -> 64 rows/block (more blocks = latency hiding; round-5 profile showed
// Occupancy 13% at 128 rows/block).
// ---------------------------------------------------------------------------
template<int TM>
__global__ __launch_bounds__(256) void gemm64(const float* __restrict__ A,
                                              const float* __restrict__ B,
                                              const float* __restrict__ bias,
                                              float* __restrict__ C,
                                              __half* __restrict__ C16,
                                              int M, int K) {
    constexpr int N = 64;
    constexpr int CG = N / 4;       // 16
    constexpr int RG = 256 / CG;    // 16
    constexpr int ROWS = RG * TM;
    constexpr int KC = 64;
    __shared__ float As[KC * ROWS];

    int tid = threadIdx.x;
    int cg = tid % CG;
    int rg = tid / CG;
    int r_base = blockIdx.x * ROWS;
    int row0 = rg * TM;

    float acc[TM][4];
#pragma unroll
    for (int m = 0; m < TM; ++m)
#pragma unroll
        for (int j = 0; j < 4; ++j) acc[m][j] = 0.f;

    for (int kc = 0; kc < K; kc += KC) {
        __syncthreads();
        constexpr int LOADS = ROWS * KC / (4 * 256);
#pragma unroll
        for (int it = 0; it < LOADS; ++it) {
            int f4 = it * 256 + tid;
            int i = f4 % ROWS;
            int j4 = f4 / ROWS;
            int grow = r_base + i;
            float4 a4 = make_float4(0.f, 0.f, 0.f, 0.f);
            if (grow < M) a4 = ld4(&A[(size_t)grow * K + kc + j4 * 4]);
            As[(j4 * 4 + 0) * ROWS + i] = a4.x;
            As[(j4 * 4 + 1) * ROWS + i] = a4.y;
            As[(j4 * 4 + 2) * ROWS + i] = a4.z;
            As[(j4 * 4 + 3) * ROWS + i] = a4.w;
        }
        __syncthreads();

        const float4* B4 = (const float4*)(B + (size_t)kc * N) + cg;
#pragma unroll
        for (int k = 0; k < KC; ++k) {
            float4 b = B4[(size_t)k * CG];
#pragma unroll
            for (int m4 = 0; m4 < TM / 4; ++m4) {
                float4 a = *(const float4*)&As[k * ROWS + row0 + m4 * 4];
                float av[4] = {a.x, a.y, a.z, a.w};
#pragma unroll
                for (int mm = 0; mm < 4; ++mm) {
                    int m = m4 * 4 + mm;
                    acc[m][0] = fmaf(av[mm], b.x, acc[m][0]);
                    acc[m][1] = fmaf(av[mm], b.y, acc[m][1]);
                    acc[m][2] = fmaf(av[mm], b.z, acc[m][2]);
                    acc[m][3] = fmaf(av[mm], b.w, acc[m][3]);
                }
            }
        }
    }

    float4 bv = make_float4(0.f, 0.f, 0.f, 0.f);
    if (bias) bv = *(const float4*)&bias[cg * 4];
#pragma unroll
    for (int m = 0; m < TM; ++m) {
        int grow = r_base + row0 + m;
        if (grow < M) {
            float4 o;
            o.x = acc[m][0] + bv.x;
            o.y = acc[m][1] + bv.y;
            o.z = acc[m][2] + bv.z;
            o.w = acc[m][3] + bv.w;
            size_t idx = (size_t)grow * N + cg * 4;
            *(float4*)&C[idx] = o;
            if (C16) {
                *(__half2*)&C16[idx] = __floats2half2_rn(o.x, o.y);
                *(__half2*)&C16[idx + 2] = __floats2half2_rn(o.z, o.w);
            }
        }
    }
}

// ---------------------------------------------------------------------------
// MFMA GEMM for post-aggregation: C[M,64] = A[M,K](fp16) @ Bt[64,K](fp16)^T
// + bias, ELU, fp16 mirror. 4 waves/block, each wave 16 rows x 64 cols.
// A-frag: lane reads A[row0+(lane&15)][k0+(lane>>4)*8 .. +8] (contig 16B).
// B-frag: lane reads Bt[t*16+(lane&15)][k0+(lane>>4)*8 .. +8] (contig 16B, L1).
// C/D layout (m89-verified): col=lane&15, row=(lane>>4)*4+reg.
// ---------------------------------------------------------------------------
__global__ __launch_bounds__(256) void mfma_postagg(const __half* __restrict__ A,
                                                    const __half* __restrict__ Bt,
                                                    const float* __restrict__ bias,
                                                    float* __restrict__ C,
                                                    __half* __restrict__ C16,
                                                    int M, int K) {
    int lane = threadIdx.x & 63;
    int wv = threadIdx.x >> 6;
    int rbase = blockIdx.x * 64 + wv * 16;
    int arow = rbase + (lane & 15);
    if (arow >= M) arow = M - 1;
    int kgrp = (lane >> 4) * 8;
    const _Float16* Ap = (const _Float16*)A + (size_t)arow * K + kgrp;
    const _Float16* Bp0 = (const _Float16*)Bt + kgrp;
    int bcol = lane & 15;

    f32x4 acc0 = {0.f, 0.f, 0.f, 0.f};
    f32x4 acc1 = {0.f, 0.f, 0.f, 0.f};
    f32x4 acc2 = {0.f, 0.f, 0.f, 0.f};
    f32x4 acc3 = {0.f, 0.f, 0.f, 0.f};

#pragma unroll 4
    for (int k0 = 0; k0 < K; k0 += 32) {
        f16x8 a = *(const f16x8*)(Ap + k0);
        f16x8 b0 = *(const f16x8*)(Bp0 + (size_t)(0 * 16 + bcol) * K + k0);
        f16x8 b1 = *(const f16x8*)(Bp0 + (size_t)(1 * 16 + bcol) * K + k0);
        f16x8 b2 = *(const f16x8*)(Bp0 + (size_t)(2 * 16 + bcol) * K + k0);
        f16x8 b3 = *(const f16x8*)(Bp0 + (size_t)(3 * 16 + bcol) * K + k0);
        acc0 = __builtin_amdgcn_mfma_f32_16x16x32_f16(a, b0, acc0, 0, 0, 0);
        acc1 = __builtin_amdgcn_mfma_f32_16x16x32_f16(a, b1, acc1, 0, 0, 0);
        acc2 = __builtin_amdgcn_mfma_f32_16x16x32_f16(a, b2, acc2, 0, 0, 0);
        acc3 = __builtin_amdgcn_mfma_f32_16x16x32_f16(a, b3, acc3, 0, 0, 0);
    }

    int crow = rbase + (lane >> 4) * 4;
    f32x4 accs[4] = {acc0, acc1, acc2, acc3};
#pragma unroll
    for (int t = 0; t < 4; ++t) {
        int col = t * 16 + (lane & 15);
        float bv = bias[col];
#pragma unroll
        for (int r = 0; r < 4; ++r) {
            int rr = crow + r;
            if (rr < M) {
                float v = accs[t][r] + bv;
                v = v > 0.f ? v : expf(v) - 1.f;
                C[(size_t)rr * 64 + col] = v;
                C16[(size_t)rr * 64 + col] = __float2half(v);
            }
        }
    }
}

// Small-N GEMM: out[n, 0:NC] = h[n, 0:64] @ W[64, NC] (+bias). 1 thread/node.
template<int NC>
__global__ void av_kernel(const float* __restrict__ h, const float* __restrict__ W,
                          const float* __restrict__ bias, float* __restrict__ out, int M) {
    int n = blockIdx.x * blockDim.x + threadIdx.x;
    if (n >= M) return;
    const float4* h4 = (const float4*)(h + (size_t)n * HID);
    float acc[NC];
#pragma unroll
    for (int c = 0; c < NC; ++c) acc[c] = bias ? bias[c] : 0.f;
#pragma unroll
    for (int k4 = 0; k4 < HID / 4; ++k4) {
        float4 hv = h4[k4];
#pragma unroll
        for (int c = 0; c < NC; ++c) {
            acc[c] = fmaf(hv.x, W[(k4 * 4 + 0) * NC + c], acc[c]);
            acc[c] = fmaf(hv.y, W[(k4 * 4 + 1) * NC + c], acc[c]);
            acc[c] = fmaf(hv.z, W[(k4 * 4 + 2) * NC + c], acc[c]);
            acc[c] = fmaf(hv.w, W[(k4 * 4 + 3) * NC + c], acc[c]);
        }
    }
#pragma unroll
    for (int c4 = 0; c4 < NC / 4; ++c4) {
        float4 o = make_float4(acc[c4 * 4 + 0], acc[c4 * 4 + 1],
                               acc[c4 * 4 + 2], acc[c4 * 4 + 3]);
        *(float4*)&out[(size_t)n * NC + c4 * 4] = o;
    }
}

// wv[lt][j,k] = sum_h W[lt][j, k*64+h] * att[lt][k,h].
__global__ void wv_kernel(const float* __restrict__ W, const float* __restrict__ att,
                          float* __restrict__ wv) {
    int lt = blockIdx.x;
    int j = threadIdx.x >> 2, k = threadIdx.x & 3;
    const float* Wp = W + (size_t)lt * HID * (KH * HID) + (size_t)j * (KH * HID) + k * HID;
    const float* ap = att + (size_t)lt * KH * HID + k * HID;
    float s = 0.f;
    for (int h = 0; h < HID; ++h) s += Wp[h] * ap[h];
    wv[(size_t)lt * HID * KH + j * KH + k] = s;
}

// Build TRANSPOSED fp16 combined weights for the post-agg MFMA GEMMs.
// wtp[h][r] (64 x 512), r = part*256 + k*64 + j; part0=pp(type0), part1=wp(type2)
// wtw[h][r] (64 x 256). Scales fold head-mean (0.25) and hetero-mean (0.5).
// alpha from gat_agg is PLAIN softmax; scaling lives only here + biases.
__global__ void build_wcomb16(const float* __restrict__ Wsrc, const float* __restrict__ cbias,
                              int l, __half* __restrict__ wtp, float* __restrict__ bp,
                              __half* __restrict__ wtw, float* __restrict__ bw) {
    int t = blockIdx.x * blockDim.x + threadIdx.x;
    if (t < 512 * 64) {
        int h = t >> 9, r = t & 511;
        int part = r >> 8;
        int k = (r & 255) >> 6, j = r & 63;
        int type = (part == 0) ? 0 : 2;
        wtp[t] = __float2half(Wsrc[(((size_t)l * 3 + type) * 64 + j) * 256 + k * 64 + h] * 0.125f);
    } else if (t < 512 * 64 + 256 * 64) {
        int u = t - 512 * 64;
        int h = u >> 8, r = u & 255;
        int k = r >> 6, j = r & 63;
        wtw[u] = __float2half(Wsrc[(((size_t)l * 3 + 1) * 64 + j) * 256 + k * 64 + h] * 0.25f);
    }
    if (t < 64) bp[t] = 0.5f * (cbias[(l * 3 + 0) * 64 + t] + cbias[(l * 3 + 2) * 64 + t]);
    else if (t >= 64 && t < 128) bw[t - 64] = cbias[(l * 3 + 1) * 64 + (t - 64)];
}

// ---------------- CSR build ----------------
__global__ void count_kernel(const int* __restrict__ dst, int* __restrict__ cnt, int E) {
    int e = blockIdx.x * blockDim.x + threadIdx.x;
    if (e < E) atomicAdd(&cnt[dst[e]], 1);
}

__global__ __launch_bounds__(1024) void scan_kernel(int* __restrict__ cw,
                                                    int* __restrict__ rowptr, int n) {
    __shared__ int wsum[16];
    __shared__ int wexc[16];
    __shared__ int carry_s;
    int tid = threadIdx.x;
    int lane = tid & 63, wv = tid >> 6;
    if (tid == 0) carry_s = 0;
    __syncthreads();
    for (int base = 0; base < n; base += 1024) {
        int i = base + tid;
        int v = (i < n) ? cw[i] : 0;
        int x = v;
#pragma unroll
        for (int off = 1; off < 64; off <<= 1) {
            int y = __shfl_up(x, off, 64);
            if (lane >= off) x += y;
        }
        if (lane == 63) wsum[wv] = x;
        __syncthreads();
        if (wv == 0 && lane < 16) {
            int s = wsum[lane];
            int xx = s;
#pragma unroll
            for (int off = 1; off < 16; off <<= 1) {
                int y = __shfl_up(xx, off, 64);
                if (lane >= off) xx += y;
            }
            wexc[lane] = xx - s;
            if (lane == 15) wsum[15] = xx;
        }
        __syncthreads();
        int excl = x - v + wexc[wv] + carry_s;
        if (i < n) { rowptr[i] = excl; cw[i] = excl; }
        if (i == n - 1) rowptr[n] = excl + v;
        int ctot = wsum[15];
        __syncthreads();
        if (tid == 0) carry_s += ctot;
        __syncthreads();
    }
}

__global__ void scatter_kernel(const int* __restrict__ src, const int* __restrict__ dst,
                               int* __restrict__ woff, int* __restrict__ perm, int E) {
    int e = blockIdx.x * blockDim.x + threadIdx.x;
    if (e < E) {
        int p = atomicAdd(&woff[dst[e]], 1);
        perm[p] = src[e];
    }
}

// ---------------------------------------------------------------------------
// Fused GAT aggregation: one wave per destination node.
// agg[d, col_off + k*64 + h] = sum_e alpha[e,k] * h16[src_e, h]   (fp16 out)
// alpha is plain softmax over the dst neighborhood.
// ---------------------------------------------------------------------------
__global__ __launch_bounds__(256) void gat_agg_kernel(
    const int* __restrict__ rowptr, const int* __restrict__ perm_src,
    const float4* __restrict__ a_s, const float4* __restrict__ a_d,
    const __half* __restrict__ h16, __half* __restrict__ agg,
    int ldagg, int col_off, int n_dst) {
    __shared__ float4 s_al[4][64];
    __shared__ int s_sr[4][64];
    int lane = threadIdx.x & 63;
    int wv = threadIdx.x >> 6;
    int d = (blockIdx.x << 2) + wv;
    if (d >= n_dst) return;
    int base = rowptr[d];
    int len = rowptr[d + 1] - base;
    float4 ad = a_d[d];

    float4 mx = make_float4(-FLT_MAX, -FLT_MAX, -FLT_MAX, -FLT_MAX);
    for (int i = lane; i < len; i += 64) {
        int s = perm_src[base + i];
        float4 as = a_s[s];
        mx.x = fmaxf(mx.x, lrelu02(as.x + ad.x));
        mx.y = fmaxf(mx.y, lrelu02(as.y + ad.y));
        mx.z = fmaxf(mx.z, lrelu02(as.z + ad.z));
        mx.w = fmaxf(mx.w, lrelu02(as.w + ad.w));
    }
#pragma unroll
    for (int off = 32; off > 0; off >>= 1) {
        mx.x = fmaxf(mx.x, __shfl_xor(mx.x, off, 64));
        mx.y = fmaxf(mx.y, __shfl_xor(mx.y, off, 64));
        mx.z = fmaxf(mx.z, __shfl_xor(mx.z, off, 64));
        mx.w = fmaxf(mx.w, __shfl_xor(mx.w, off, 64));
    }

    float4 sm = make_float4(0.f, 0.f, 0.f, 0.f);
    for (int i = lane; i < len; i += 64) {
        int s = perm_src[base + i];
        float4 as = a_s[s];
        sm.x += expf(lrelu02(as.x + ad.x) - mx.x);
        sm.y += expf(lrelu02(as.y + ad.y) - mx.y);
        sm.z += expf(lrelu02(as.z + ad.z) - mx.z);
        sm.w += expf(lrelu02(as.w + ad.w) - mx.w);
    }
#pragma unroll
    for (int off = 32; off > 0; off >>= 1) {
        sm.x += __shfl_xor(sm.x, off, 64);
        sm.y += __shfl_xor(sm.y, off, 64);
        sm.z += __shfl_xor(sm.z, off, 64);
        sm.w += __shfl_xor(sm.w, off, 64);
    }
    float4 inv;
    inv.x = len ? 1.0f / sm.x : 0.f;
    inv.y = len ? 1.0f / sm.y : 0.f;
    inv.z = len ? 1.0f / sm.z : 0.f;
    inv.w = len ? 1.0f / sm.w : 0.f;

    float a0 = 0.f, a1 = 0.f, a2 = 0.f, a3 = 0.f;
    for (int c0 = 0; c0 < len; c0 += 64) {
        int i = c0 + lane;
        if (i < len) {
            int s = perm_src[base + i];
            float4 as = a_s[s];
            float4 al;
            al.x = expf(lrelu02(as.x + ad.x) - mx.x) * inv.x;
            al.y = expf(lrelu02(as.y + ad.y) - mx.y) * inv.y;
            al.z = expf(lrelu02(as.z + ad.z) - mx.z) * inv.z;
            al.w = expf(lrelu02(as.w + ad.w) - mx.w) * inv.w;
            s_al[wv][lane] = al;
            s_sr[wv][lane] = s;
        }
        int cnt = min(64, len - c0);
        for (int j = 0; j < cnt; ++j) {
            int sj = s_sr[wv][j];
            float4 al = s_al[wv][j];
            float hv = __half2float(h16[(size_t)sj * HID + lane]);
            a0 = fmaf(al.x, hv, a0);
            a1 = fmaf(al.y, hv, a1);
            a2 = fmaf(al.z, hv, a2);
            a3 = fmaf(al.w, hv, a3);
        }
    }
    size_t ob = (size_t)d * ldagg + col_off + lane;
    agg[ob]       = __float2half(a0);
    agg[ob + 64]  = __float2half(a1);
    agg[ob + 128] = __float2half(a2);
    agg[ob + 192] = __float2half(a3);
}

extern "C" void kernel_launch(void* const* d_in, const int* in_sizes, int n_in,
                              void* d_out, int out_size, void* d_ws, size_t ws_size,
                              hipStream_t stream) {
    const float* x_p    = (const float*)d_in[0];
    const float* x_w    = (const float*)d_in[1];
    const float* Wpp    = (const float*)d_in[2];
    const float* bpp    = (const float*)d_in[3];
    const float* Wpw    = (const float*)d_in[4];
    const float* bpw    = (const float*)d_in[5];
    const float* Wsrc   = (const float*)d_in[6];   // (2,3,64,256)
    const float* Wdst   = (const float*)d_in[7];   // (2,3,64,256)
    const float* Asrc   = (const float*)d_in[8];   // (2,3,4,64)
    const float* Adst   = (const float*)d_in[9];   // (2,3,4,64)
    const float* cbias  = (const float*)d_in[10];  // (2,3,64)
    const float* Wpostp = (const float*)d_in[11];
    const float* bpostp = (const float*)d_in[12];
    const float* Wpostw = (const float*)d_in[13];
    const float* bpostw = (const float*)d_in[14];
    const int*   ei_pp  = (const int*)d_in[15];    // (2,E): src row then dst row
    const int*   ei_pw  = (const int*)d_in[16];
    const int*   ei_wp  = (const int*)d_in[17];

    char* base = (char*)d_ws;
    size_t off = 0;
    auto alloc = [&](size_t bytes) -> void* {
        void* p = base + off;
        off = (off + bytes + 15) & ~(size_t)15;
        return p;
    };

    float*  h_p   = (float*)alloc((size_t)N_P * HID * 4);
    float*  h_w   = (float*)alloc((size_t)N_W * HID * 4);
    __half* h16_p = (__half*)alloc((size_t)N_P * HID * 2);
    __half* h16_w = (__half*)alloc((size_t)N_W * HID * 2);
    float*  a_s   = (float*)alloc((size_t)N_P * KH * 4);
    float*  a_d   = (float*)alloc((size_t)N_P * KH * 4);
    __half* agg_p = (__half*)alloc((size_t)N_P * 512 * 2);
    __half* agg_w = (__half*)alloc((size_t)N_W * 256 * 2);
    float*  wv_s  = (float*)alloc((size_t)LL * 3 * HID * KH * 4);
    float*  wv_d  = (float*)alloc((size_t)LL * 3 * HID * KH * 4);
    __half* wtp   = (__half*)alloc(64 * 512 * 2);
    __half* wtw   = (__half*)alloc(64 * 256 * 2);
    float*  bp    = (float*)alloc(64 * 4);
    float*  bw    = (float*)alloc(64 * 4);
    int*    rp_pp = (int*)alloc((N_P + 1) * 4);
    int*    cw_pp = (int*)alloc(N_P * 4);
    int*    rp_pw = (int*)alloc((N_W + 1) * 4);
    int*    cw_pw = (int*)alloc(N_W * 4);
    int*    rp_wp = (int*)alloc((N_P + 1) * 4);
    int*    cw_wp = (int*)alloc(N_P * 4);
    int*    pm_pp = (int*)alloc((size_t)E_PP * 4);
    int*    pm_pw = (int*)alloc((size_t)E_PW * 4);
    int*    pm_wp = (int*)alloc((size_t)E_WP * 4);

    auto cdiv = [](long long a, long long b) { return (int)((a + b - 1) / b); };

    // attention weight vectors
    wv_kernel<<<LL * 3, 256, 0, stream>>>(Wsrc, Asrc, wv_s);
    wv_kernel<<<LL * 3, 256, 0, stream>>>(Wdst, Adst, wv_d);

    // CSR build (edges identical across layers)
    struct CsrDesc { const int* ei; int E, n_dst; int *rp, *cw, *pm; };
    CsrDesc csr[3] = {
        { ei_pp, E_PP, N_P, rp_pp, cw_pp, pm_pp },
        { ei_pw, E_PW, N_W, rp_pw, cw_pw, pm_pw },
        { ei_wp, E_WP, N_P, rp_wp, cw_wp, pm_wp },
    };
    for (int t = 0; t < 3; ++t) {
        const int* src = csr[t].ei;
        const int* dst = csr[t].ei + csr[t].E;
        hipMemsetAsync(csr[t].cw, 0, (size_t)csr[t].n_dst * 4, stream);
        count_kernel<<<cdiv(csr[t].E, 256), 256, 0, stream>>>(dst, csr[t].cw, csr[t].E);
        scan_kernel<<<1, 1024, 0, stream>>>(csr[t].cw, csr[t].rp, csr[t].n_dst);
        scatter_kernel<<<cdiv(csr[t].E, 256), 256, 0, stream>>>(src, dst, csr[t].cw, csr[t].pm, csr[t].E);
    }

    // input projections (fp32 h + fp16 mirror), 64 rows/block
    gemm64<4><<<cdiv(N_P, 64), 256, 0, stream>>>(x_p, Wpp, bpp, h_p, h16_p, N_P, D_P);
    gemm64<4><<<cdiv(N_W, 64), 256, 0, stream>>>(x_w, Wpw, bpw, h_w, h16_w, N_W, D_W);

    for (int l = 0; l < LL; ++l) {
        build_wcomb16<<<cdiv(512 * 64 + 256 * 64, 256), 256, 0, stream>>>(
            Wsrc, cbias, l, wtp, bp, wtw, bw);

        // pp: src=p, dst=p -> agg_p cols [0,256)
        int lt = l * 3 + 0;
        av_kernel<4><<<cdiv(N_P, 256), 256, 0, stream>>>(h_p, wv_s + (size_t)lt * 256, nullptr, a_s, N_P);
        av_kernel<4><<<cdiv(N_P, 256), 256, 0, stream>>>(h_p, wv_d + (size_t)lt * 256, nullptr, a_d, N_P);
        gat_agg_kernel<<<cdiv(N_P, 4), 256, 0, stream>>>(
            rp_pp, pm_pp, (const float4*)a_s, (const float4*)a_d, h16_p, agg_p, 512, 0, N_P);

        // pw: src=p, dst=w -> agg_w cols [0,256)
        lt = l * 3 + 1;
        av_kernel<4><<<cdiv(N_P, 256), 256, 0, stream>>>(h_p, wv_s + (size_t)lt * 256, nullptr, a_s, N_P);
        av_kernel<4><<<cdiv(N_W, 256), 256, 0, stream>>>(h_w, wv_d + (size_t)lt * 256, nullptr, a_d, N_W);
        gat_agg_kernel<<<cdiv(N_W, 4), 256, 0, stream>>>(
            rp_pw, pm_pw, (const float4*)a_s, (const float4*)a_d, h16_p, agg_w, 256, 0, N_W);

        // wp: src=w, dst=p -> agg_p cols [256,512)
        lt = l * 3 + 2;
        av_kernel<4><<<cdiv(N_W, 256), 256, 0, stream>>>(h_w, wv_s + (size_t)lt * 256, nullptr, a_s, N_W);
        av_kernel<4><<<cdiv(N_P, 256), 256, 0, stream>>>(h_p, wv_d + (size_t)lt * 256, nullptr, a_d, N_P);
        gat_agg_kernel<<<cdiv(N_P, 4), 256, 0, stream>>>(
            rp_wp, pm_wp, (const float4*)a_s, (const float4*)a_d, h16_w, agg_p, 512, 256, N_P);

        // post-aggregation projections: MFMA fp16 with fused bias + ELU
        mfma_postagg<<<cdiv(N_P, 64), 256, 0, stream>>>(agg_p, wtp, bp, h_p, h16_p, N_P, 512);
        mfma_postagg<<<cdiv(N_W, 64), 256, 0, stream>>>(agg_w, wtw, bw, h_w, h16_w, N_W, 256);
    }

    float* out_p = (float*)d_out;
    float* out_w = out_p + (size_t)N_P * OUTD;
    av_kernel<8><<<cdiv(N_P, 256), 256, 0, stream>>>(h_p, Wpostp, bpostp, out_p, N_P);
    av_kernel<8><<<cdiv(N_W, 256), 256, 0, stream>>>(h_w, Wpostw, bpostw, out_w, N_W);
}

// Round 7
// 582.556 us; speedup vs baseline: 2.3074x; 1.2125x over previous
//
#include <hip/hip_runtime.h>
#include <hip/hip_fp16.h>
#include <cfloat>
#include <cmath>

#define N_P 50000
#define N_W 10000
#define D_P 256
#define D_W 128
#define HID 64
#define OUTD 8
#define KH 4
#define LL 2
#define E_PP 500000
#define E_PW 150000
#define E_WP 150000

typedef _Float16 f16x8 __attribute__((ext_vector_type(8)));
typedef float f32x4 __attribute__((ext_vector_type(4)));

__device__ inline float lrelu02(float v) { return v > 0.f ? v : 0.2f * v; }
__device__ inline float4 ld4(const float* p) { return *(const float4*)p; }

// ---------------------------------------------------------------------------
// fp32 tiled GEMM for input projections: C[M,64] = A[M,K] @ B[K,64] + bias.
// ---------------------------------------------------------------------------
template<int TM>
__global__ __launch_bounds__(256) void gemm64(const float* __restrict__ A,
                                              const float* __restrict__ B,
                                              const float* __restrict__ bias,
                                              float* __restrict__ C,
                                              __half* __restrict__ C16,
                                              int M, int K) {
    constexpr int N = 64;
    constexpr int CG = N / 4;
    constexpr int RG = 256 / CG;
    constexpr int ROWS = RG * TM;
    constexpr int KC = 64;
    __shared__ float As[KC * ROWS];

    int tid = threadIdx.x;
    int cg = tid % CG;
    int rg = tid / CG;
    int r_base = blockIdx.x * ROWS;
    int row0 = rg * TM;

    float acc[TM][4];
#pragma unroll
    for (int m = 0; m < TM; ++m)
#pragma unroll
        for (int j = 0; j < 4; ++j) acc[m][j] = 0.f;

    for (int kc = 0; kc < K; kc += KC) {
        __syncthreads();
        constexpr int LOADS = ROWS * KC / (4 * 256);
#pragma unroll
        for (int it = 0; it < LOADS; ++it) {
            int f4 = it * 256 + tid;
            int i = f4 % ROWS;
            int j4 = f4 / ROWS;
            int grow = r_base + i;
            float4 a4 = make_float4(0.f, 0.f, 0.f, 0.f);
            if (grow < M) a4 = ld4(&A[(size_t)grow * K + kc + j4 * 4]);
            As[(j4 * 4 + 0) * ROWS + i] = a4.x;
            As[(j4 * 4 + 1) * ROWS + i] = a4.y;
            As[(j4 * 4 + 2) * ROWS + i] = a4.z;
            As[(j4 * 4 + 3) * ROWS + i] = a4.w;
        }
        __syncthreads();

        const float4* B4 = (const float4*)(B + (size_t)kc * N) + cg;
#pragma unroll
        for (int k = 0; k < KC; ++k) {
            float4 b = B4[(size_t)k * CG];
#pragma unroll
            for (int m4 = 0; m4 < TM / 4; ++m4) {
                float4 a = *(const float4*)&As[k * ROWS + row0 + m4 * 4];
                float av[4] = {a.x, a.y, a.z, a.w};
#pragma unroll
                for (int mm = 0; mm < 4; ++mm) {
                    int m = m4 * 4 + mm;
                    acc[m][0] = fmaf(av[mm], b.x, acc[m][0]);
                    acc[m][1] = fmaf(av[mm], b.y, acc[m][1]);
                    acc[m][2] = fmaf(av[mm], b.z, acc[m][2]);
                    acc[m][3] = fmaf(av[mm], b.w, acc[m][3]);
                }
            }
        }
    }

    float4 bv = make_float4(0.f, 0.f, 0.f, 0.f);
    if (bias) bv = *(const float4*)&bias[cg * 4];
#pragma unroll
    for (int m = 0; m < TM; ++m) {
        int grow = r_base + row0 + m;
        if (grow < M) {
            float4 o;
            o.x = acc[m][0] + bv.x;
            o.y = acc[m][1] + bv.y;
            o.z = acc[m][2] + bv.z;
            o.w = acc[m][3] + bv.w;
            size_t idx = (size_t)grow * N + cg * 4;
            *(float4*)&C[idx] = o;
            if (C16) {
                *(__half2*)&C16[idx] = __floats2half2_rn(o.x, o.y);
                *(__half2*)&C16[idx + 2] = __floats2half2_rn(o.z, o.w);
            }
        }
    }
}

// ---------------------------------------------------------------------------
// MFMA GEMM for post-aggregation (fp16 A, fp16 Bt, fp32 acc, bias+ELU fused).
// ---------------------------------------------------------------------------
__global__ __launch_bounds__(256) void mfma_postagg(const __half* __restrict__ A,
                                                    const __half* __restrict__ Bt,
                                                    const float* __restrict__ bias,
                                                    float* __restrict__ C,
                                                    __half* __restrict__ C16,
                                                    int M, int K) {
    int lane = threadIdx.x & 63;
    int wv = threadIdx.x >> 6;
    int rbase = blockIdx.x * 64 + wv * 16;
    int arow = rbase + (lane & 15);
    if (arow >= M) arow = M - 1;
    int kgrp = (lane >> 4) * 8;
    const _Float16* Ap = (const _Float16*)A + (size_t)arow * K + kgrp;
    const _Float16* Bp0 = (const _Float16*)Bt + kgrp;
    int bcol = lane & 15;

    f32x4 acc0 = {0.f, 0.f, 0.f, 0.f};
    f32x4 acc1 = {0.f, 0.f, 0.f, 0.f};
    f32x4 acc2 = {0.f, 0.f, 0.f, 0.f};
    f32x4 acc3 = {0.f, 0.f, 0.f, 0.f};

#pragma unroll 4
    for (int k0 = 0; k0 < K; k0 += 32) {
        f16x8 a = *(const f16x8*)(Ap + k0);
        f16x8 b0 = *(const f16x8*)(Bp0 + (size_t)(0 * 16 + bcol) * K + k0);
        f16x8 b1 = *(const f16x8*)(Bp0 + (size_t)(1 * 16 + bcol) * K + k0);
        f16x8 b2 = *(const f16x8*)(Bp0 + (size_t)(2 * 16 + bcol) * K + k0);
        f16x8 b3 = *(const f16x8*)(Bp0 + (size_t)(3 * 16 + bcol) * K + k0);
        acc0 = __builtin_amdgcn_mfma_f32_16x16x32_f16(a, b0, acc0, 0, 0, 0);
        acc1 = __builtin_amdgcn_mfma_f32_16x16x32_f16(a, b1, acc1, 0, 0, 0);
        acc2 = __builtin_amdgcn_mfma_f32_16x16x32_f16(a, b2, acc2, 0, 0, 0);
        acc3 = __builtin_amdgcn_mfma_f32_16x16x32_f16(a, b3, acc3, 0, 0, 0);
    }

    int crow = rbase + (lane >> 4) * 4;
    f32x4 accs[4] = {acc0, acc1, acc2, acc3};
#pragma unroll
    for (int t = 0; t < 4; ++t) {
        int col = t * 16 + (lane & 15);
        float bv = bias[col];
#pragma unroll
        for (int r = 0; r < 4; ++r) {
            int rr = crow + r;
            if (rr < M) {
                float v = accs[t][r] + bv;
                v = v > 0.f ? v : expf(v) - 1.f;
                C[(size_t)rr * 64 + col] = v;
                C16[(size_t)rr * 64 + col] = __float2half(v);
            }
        }
    }
}

// Small-N GEMM: out[n, 0:NC] = h[n, 0:64] @ W[64, NC] (+bias). 1 thread/node.
template<int NC>
__global__ void av_kernel(const float* __restrict__ h, const float* __restrict__ W,
                          const float* __restrict__ bias, float* __restrict__ out, int M) {
    int n = blockIdx.x * blockDim.x + threadIdx.x;
    if (n >= M) return;
    const float4* h4 = (const float4*)(h + (size_t)n * HID);
    float acc[NC];
#pragma unroll
    for (int c = 0; c < NC; ++c) acc[c] = bias ? bias[c] : 0.f;
#pragma unroll
    for (int k4 = 0; k4 < HID / 4; ++k4) {
        float4 hv = h4[k4];
#pragma unroll
        for (int c = 0; c < NC; ++c) {
            acc[c] = fmaf(hv.x, W[(k4 * 4 + 0) * NC + c], acc[c]);
            acc[c] = fmaf(hv.y, W[(k4 * 4 + 1) * NC + c], acc[c]);
            acc[c] = fmaf(hv.z, W[(k4 * 4 + 2) * NC + c], acc[c]);
            acc[c] = fmaf(hv.w, W[(k4 * 4 + 3) * NC + c], acc[c]);
        }
    }
#pragma unroll
    for (int c4 = 0; c4 < NC / 4; ++c4) {
        float4 o = make_float4(acc[c4 * 4 + 0], acc[c4 * 4 + 1],
                               acc[c4 * 4 + 2], acc[c4 * 4 + 3]);
        *(float4*)&out[(size_t)n * NC + c4 * 4] = o;
    }
}

// Fused multi-target attention dots: oJ[n] = h[n,0:64] @ WJ[64,4]. NJ jobs.
template<int NJ>
__global__ void av_multi(const float* __restrict__ h,
                         const float* __restrict__ W0, const float* __restrict__ W1,
                         const float* __restrict__ W2, const float* __restrict__ W3,
                         float4* __restrict__ o0, float4* __restrict__ o1,
                         float4* __restrict__ o2, float4* __restrict__ o3, int M) {
    int n = blockIdx.x * blockDim.x + threadIdx.x;
    if (n >= M) return;
    const float4* h4 = (const float4*)(h + (size_t)n * HID);
    float a0[4] = {0.f, 0.f, 0.f, 0.f}, a1[4] = {0.f, 0.f, 0.f, 0.f};
    float a2[4] = {0.f, 0.f, 0.f, 0.f}, a3[4] = {0.f, 0.f, 0.f, 0.f};
#pragma unroll
    for (int k4 = 0; k4 < 16; ++k4) {
        float4 hv = h4[k4];
        float hvv[4] = {hv.x, hv.y, hv.z, hv.w};
#pragma unroll
        for (int r = 0; r < 4; ++r) {
            int f = k4 * 4 + r;
            float x = hvv[r];
#pragma unroll
            for (int c = 0; c < 4; ++c) a0[c] = fmaf(x, W0[f * 4 + c], a0[c]);
#pragma unroll
            for (int c = 0; c < 4; ++c) a1[c] = fmaf(x, W1[f * 4 + c], a1[c]);
            if (NJ > 2) {
#pragma unroll
                for (int c = 0; c < 4; ++c) a2[c] = fmaf(x, W2[f * 4 + c], a2[c]);
#pragma unroll
                for (int c = 0; c < 4; ++c) a3[c] = fmaf(x, W3[f * 4 + c], a3[c]);
            }
        }
    }
    o0[n] = make_float4(a0[0], a0[1], a0[2], a0[3]);
    o1[n] = make_float4(a1[0], a1[1], a1[2], a1[3]);
    if (NJ > 2) {
        o2[n] = make_float4(a2[0], a2[1], a2[2], a2[3]);
        o3[n] = make_float4(a3[0], a3[1], a3[2], a3[3]);
    }
}

// wv[lt][j,k] = sum_h W[lt][j, k*64+h] * att[lt][k,h].
__global__ void wv_kernel(const float* __restrict__ W, const float* __restrict__ att,
                          float* __restrict__ wv) {
    int lt = blockIdx.x;
    int j = threadIdx.x >> 2, k = threadIdx.x & 3;
    const float* Wp = W + (size_t)lt * HID * (KH * HID) + (size_t)j * (KH * HID) + k * HID;
    const float* ap = att + (size_t)lt * KH * HID + k * HID;
    float s = 0.f;
    for (int h = 0; h < HID; ++h) s += Wp[h] * ap[h];
    wv[(size_t)lt * HID * KH + j * KH + k] = s;
}

// Transposed fp16 combined weights; head-mean/hetero-mean folded here ONLY.
__global__ void build_wcomb16(const float* __restrict__ Wsrc, const float* __restrict__ cbias,
                              int l, __half* __restrict__ wtp, float* __restrict__ bp,
                              __half* __restrict__ wtw, float* __restrict__ bw) {
    int t = blockIdx.x * blockDim.x + threadIdx.x;
    if (t < 512 * 64) {
        int h = t >> 9, r = t & 511;
        int part = r >> 8;
        int k = (r & 255) >> 6, j = r & 63;
        int type = (part == 0) ? 0 : 2;
        wtp[t] = __float2half(Wsrc[(((size_t)l * 3 + type) * 64 + j) * 256 + k * 64 + h] * 0.125f);
    } else if (t < 512 * 64 + 256 * 64) {
        int u = t - 512 * 64;
        int h = u >> 8, r = u & 255;
        int k = r >> 6, j = r & 63;
        wtw[u] = __float2half(Wsrc[(((size_t)l * 3 + 1) * 64 + j) * 256 + k * 64 + h] * 0.25f);
    }
    if (t < 64) bp[t] = 0.5f * (cbias[(l * 3 + 0) * 64 + t] + cbias[(l * 3 + 2) * 64 + t]);
    else if (t >= 64 && t < 128) bw[t - 64] = cbias[(l * 3 + 1) * 64 + (t - 64)];
}

// ---------------- CSR build ----------------
__global__ void count_kernel(const int* __restrict__ dst, int* __restrict__ cnt, int E) {
    int e = blockIdx.x * blockDim.x + threadIdx.x;
    if (e < E) atomicAdd(&cnt[dst[e]], 1);
}

__global__ __launch_bounds__(1024) void block_sum_kernel(const int* __restrict__ cnt,
                                                         int* __restrict__ bsum, int n) {
    __shared__ int wsum[16];
    int tid = threadIdx.x, lane = tid & 63, wv = tid >> 6;
    int i = blockIdx.x * 1024 + tid;
    int v = (i < n) ? cnt[i] : 0;
#pragma unroll
    for (int off = 32; off > 0; off >>= 1) v += __shfl_xor(v, off, 64);
    if (lane == 0) wsum[wv] = v;
    __syncthreads();
    if (tid == 0) {
        int t = 0;
#pragma unroll
        for (int k = 0; k < 16; ++k) t += wsum[k];
        bsum[blockIdx.x] = t;
    }
}

// single block: exclusive scan of bsum[0..nb) in place (nb <= 1024)
__global__ __launch_bounds__(1024) void scan_bsums_kernel(int* __restrict__ bsum, int nb) {
    __shared__ int wsum[16], wexc[16];
    int tid = threadIdx.x, lane = tid & 63, wv = tid >> 6;
    int v = (tid < nb) ? bsum[tid] : 0;
    int x = v;
#pragma unroll
    for (int off = 1; off < 64; off <<= 1) {
        int y = __shfl_up(x, off, 64);
        if (lane >= off) x += y;
    }
    if (lane == 63) wsum[wv] = x;
    __syncthreads();
    if (wv == 0 && lane < 16) {
        int s = wsum[lane];
        int xx = s;
#pragma unroll
        for (int off = 1; off < 16; off <<= 1) {
            int y = __shfl_up(xx, off, 16);
            if (lane >= off) xx += y;
        }
        wexc[lane] = xx - s;
    }
    __syncthreads();
    if (tid < nb) bsum[tid] = x - v + wexc[wv];
}

__global__ __launch_bounds__(1024) void block_scan_kernel(const int* __restrict__ cnt,
                                                          const int* __restrict__ bsum,
                                                          int* __restrict__ rowptr,
                                                          int* __restrict__ woff, int n) {
    __shared__ int wsum[16], wexc[16];
    int tid = threadIdx.x, lane = tid & 63, wv = tid >> 6;
    int i = blockIdx.x * 1024 + tid;
    int v = (i < n) ? cnt[i] : 0;
    int x = v;
#pragma unroll
    for (int off = 1; off < 64; off <<= 1) {
        int y = __shfl_up(x, off, 64);
        if (lane >= off) x += y;
    }
    if (lane == 63) wsum[wv] = x;
    __syncthreads();
    if (wv == 0 && lane < 16) {
        int s = wsum[lane];
        int xx = s;
#pragma unroll
        for (int off = 1; off < 16; off <<= 1) {
            int y = __shfl_up(xx, off, 16);
            if (lane >= off) xx += y;
        }
        wexc[lane] = xx - s;
    }
    __syncthreads();
    int excl = x - v + wexc[wv] + bsum[blockIdx.x];
    if (i < n) { rowptr[i] = excl; woff[i] = excl; }
    if (i == n - 1) rowptr[n] = excl + v;
}

__global__ void scatter_kernel(const int* __restrict__ src, const int* __restrict__ dst,
                               int* __restrict__ woff, int* __restrict__ perm, int E) {
    int e = blockIdx.x * blockDim.x + threadIdx.x;
    if (e < E) {
        int p = atomicAdd(&woff[dst[e]], 1);
        perm[p] = src[e];
    }
}

// ---------------------------------------------------------------------------
// Softmax stats + alpha: ONE THREAD per dst node (avg degree ~10 -> dense
// lanes, no reductions). 3 serial passes; writes alpha[edge] (plain softmax).
// ---------------------------------------------------------------------------
__global__ void gat_stats_kernel(const int* __restrict__ rowptr,
                                 const int* __restrict__ perm_src,
                                 const float4* __restrict__ a_s,
                                 const float4* __restrict__ a_d,
                                 float4* __restrict__ alpha, int n_dst) {
    int d = blockIdx.x * blockDim.x + threadIdx.x;
    if (d >= n_dst) return;
    int base = rowptr[d], end = rowptr[d + 1];
    float4 ad = a_d[d];
    float4 mx = make_float4(-FLT_MAX, -FLT_MAX, -FLT_MAX, -FLT_MAX);
    for (int i = base; i < end; ++i) {
        float4 as = a_s[perm_src[i]];
        mx.x = fmaxf(mx.x, lrelu02(as.x + ad.x));
        mx.y = fmaxf(mx.y, lrelu02(as.y + ad.y));
        mx.z = fmaxf(mx.z, lrelu02(as.z + ad.z));
        mx.w = fmaxf(mx.w, lrelu02(as.w + ad.w));
    }
    float4 sm = make_float4(0.f, 0.f, 0.f, 0.f);
    for (int i = base; i < end; ++i) {
        float4 as = a_s[perm_src[i]];
        float4 t;
        t.x = __expf(lrelu02(as.x + ad.x) - mx.x);
        t.y = __expf(lrelu02(as.y + ad.y) - mx.y);
        t.z = __expf(lrelu02(as.z + ad.z) - mx.z);
        t.w = __expf(lrelu02(as.w + ad.w) - mx.w);
        alpha[i] = t;
        sm.x += t.x; sm.y += t.y; sm.z += t.z; sm.w += t.w;
    }
    float4 inv;
    inv.x = 1.f / sm.x; inv.y = 1.f / sm.y; inv.z = 1.f / sm.z; inv.w = 1.f / sm.w;
    for (int i = base; i < end; ++i) {
        float4 t = alpha[i];
        t.x *= inv.x; t.y *= inv.y; t.z *= inv.z; t.w *= inv.w;
        alpha[i] = t;
    }
}

// ---------------------------------------------------------------------------
// Message aggregation: one wave per dst node, lane = feature.
// agg[d, col_off + k*64 + h] = sum_e alpha[e,k] * h16[src_e, h]
// ---------------------------------------------------------------------------
__global__ __launch_bounds__(256) void gat_msg_kernel(
    const int* __restrict__ rowptr, const int* __restrict__ perm_src,
    const float4* __restrict__ alpha, const __half* __restrict__ h16,
    __half* __restrict__ agg, int ldagg, int col_off, int n_dst) {
    __shared__ float4 s_al[4][64];
    __shared__ int s_sr[4][64];
    int lane = threadIdx.x & 63;
    int wv = threadIdx.x >> 6;
    int d = (blockIdx.x << 2) + wv;
    if (d >= n_dst) return;
    int base = rowptr[d];
    int len = rowptr[d + 1] - base;

    float a0 = 0.f, a1 = 0.f, a2 = 0.f, a3 = 0.f;
    for (int c0 = 0; c0 < len; c0 += 64) {
        int i = c0 + lane;
        if (i < len) {
            s_sr[wv][lane] = perm_src[base + i];
            s_al[wv][lane] = alpha[base + i];
        }
        int cnt = min(64, len - c0);
        int j = 0;
        for (; j + 4 <= cnt; j += 4) {
            int sj0 = s_sr[wv][j], sj1 = s_sr[wv][j + 1];
            int sj2 = s_sr[wv][j + 2], sj3 = s_sr[wv][j + 3];
            float h0 = __half2float(h16[(size_t)sj0 * HID + lane]);
            float h1 = __half2float(h16[(size_t)sj1 * HID + lane]);
            float h2 = __half2float(h16[(size_t)sj2 * HID + lane]);
            float h3 = __half2float(h16[(size_t)sj3 * HID + lane]);
            float4 l0 = s_al[wv][j], l1 = s_al[wv][j + 1];
            float4 l2 = s_al[wv][j + 2], l3 = s_al[wv][j + 3];
            a0 = fmaf(l0.x, h0, a0); a1 = fmaf(l0.y, h0, a1);
            a2 = fmaf(l0.z, h0, a2); a3 = fmaf(l0.w, h0, a3);
            a0 = fmaf(l1.x, h1, a0); a1 = fmaf(l1.y, h1, a1);
            a2 = fmaf(l1.z, h1, a2); a3 = fmaf(l1.w, h1, a3);
            a0 = fmaf(l2.x, h2, a0); a1 = fmaf(l2.y, h2, a1);
            a2 = fmaf(l2.z, h2, a2); a3 = fmaf(l2.w, h2, a3);
            a0 = fmaf(l3.x, h3, a0); a1 = fmaf(l3.y, h3, a1);
            a2 = fmaf(l3.z, h3, a2); a3 = fmaf(l3.w, h3, a3);
        }
        for (; j < cnt; ++j) {
            int sj = s_sr[wv][j];
            float4 al = s_al[wv][j];
            float hv = __half2float(h16[(size_t)sj * HID + lane]);
            a0 = fmaf(al.x, hv, a0); a1 = fmaf(al.y, hv, a1);
            a2 = fmaf(al.z, hv, a2); a3 = fmaf(al.w, hv, a3);
        }
    }
    size_t ob = (size_t)d * ldagg + col_off + lane;
    agg[ob]       = __float2half(a0);
    agg[ob + 64]  = __float2half(a1);
    agg[ob + 128] = __float2half(a2);
    agg[ob + 192] = __float2half(a3);
}

extern "C" void kernel_launch(void* const* d_in, const int* in_sizes, int n_in,
                              void* d_out, int out_size, void* d_ws, size_t ws_size,
                              hipStream_t stream) {
    const float* x_p    = (const float*)d_in[0];
    const float* x_w    = (const float*)d_in[1];
    const float* Wpp    = (const float*)d_in[2];
    const float* bpp    = (const float*)d_in[3];
    const float* Wpw    = (const float*)d_in[4];
    const float* bpw    = (const float*)d_in[5];
    const float* Wsrc   = (const float*)d_in[6];   // (2,3,64,256)
    const float* Wdst   = (const float*)d_in[7];   // (2,3,64,256)
    const float* Asrc   = (const float*)d_in[8];   // (2,3,4,64)
    const float* Adst   = (const float*)d_in[9];   // (2,3,4,64)
    const float* cbias  = (const float*)d_in[10];  // (2,3,64)
    const float* Wpostp = (const float*)d_in[11];
    const float* bpostp = (const float*)d_in[12];
    const float* Wpostw = (const float*)d_in[13];
    const float* bpostw = (const float*)d_in[14];
    const int*   ei_pp  = (const int*)d_in[15];    // (2,E): src row then dst row
    const int*   ei_pw  = (const int*)d_in[16];
    const int*   ei_wp  = (const int*)d_in[17];

    char* base = (char*)d_ws;
    size_t off = 0;
    auto alloc = [&](size_t bytes) -> void* {
        void* p = base + off;
        off = (off + bytes + 15) & ~(size_t)15;
        return p;
    };

    float*  h_p    = (float*)alloc((size_t)N_P * HID * 4);
    float*  h_w    = (float*)alloc((size_t)N_W * HID * 4);
    __half* h16_p  = (__half*)alloc((size_t)N_P * HID * 2);
    __half* h16_w  = (__half*)alloc((size_t)N_W * HID * 2);
    __half* agg_p  = (__half*)alloc((size_t)N_P * 512 * 2);
    __half* agg_w  = (__half*)alloc((size_t)N_W * 256 * 2);
    float*  wv_s   = (float*)alloc((size_t)LL * 3 * HID * KH * 4);
    float*  wv_d   = (float*)alloc((size_t)LL * 3 * HID * KH * 4);
    __half* wtp    = (__half*)alloc(64 * 512 * 2);
    __half* wtw    = (__half*)alloc(64 * 256 * 2);
    float*  bp     = (float*)alloc(64 * 4);
    float*  bw     = (float*)alloc(64 * 4);
    float*  a_pp_s = (float*)alloc((size_t)N_P * KH * 4);
    float*  a_pp_d = (float*)alloc((size_t)N_P * KH * 4);
    float*  a_pw_s = (float*)alloc((size_t)N_P * KH * 4);
    float*  a_pw_d = (float*)alloc((size_t)N_W * KH * 4);
    float*  a_wp_s = (float*)alloc((size_t)N_W * KH * 4);
    float*  a_wp_d = (float*)alloc((size_t)N_P * KH * 4);
    float*  al_pp  = (float*)alloc((size_t)E_PP * KH * 4);
    float*  al_pw  = (float*)alloc((size_t)E_PW * KH * 4);
    float*  al_wp  = (float*)alloc((size_t)E_WP * KH * 4);
    int*    rp_pp  = (int*)alloc((N_P + 1) * 4);
    int*    cn_pp  = (int*)alloc(N_P * 4);
    int*    wo_pp  = (int*)alloc(N_P * 4);
    int*    rp_pw  = (int*)alloc((N_W + 1) * 4);
    int*    cn_pw  = (int*)alloc(N_W * 4);
    int*    wo_pw  = (int*)alloc(N_W * 4);
    int*    rp_wp  = (int*)alloc((N_P + 1) * 4);
    int*    cn_wp  = (int*)alloc(N_P * 4);
    int*    wo_wp  = (int*)alloc(N_P * 4);
    int*    pm_pp  = (int*)alloc((size_t)E_PP * 4);
    int*    pm_pw  = (int*)alloc((size_t)E_PW * 4);
    int*    pm_wp  = (int*)alloc((size_t)E_WP * 4);
    int*    bsum   = (int*)alloc(1024 * 4);

    auto cdiv = [](long long a, long long b) { return (int)((a + b - 1) / b); };

    wv_kernel<<<LL * 3, 256, 0, stream>>>(Wsrc, Asrc, wv_s);
    wv_kernel<<<LL * 3, 256, 0, stream>>>(Wdst, Adst, wv_d);

    // CSR build (edges identical across layers)
    struct CsrDesc { const int* ei; int E, n_dst; int *rp, *cn, *wo, *pm; };
    CsrDesc csr[3] = {
        { ei_pp, E_PP, N_P, rp_pp, cn_pp, wo_pp, pm_pp },
        { ei_pw, E_PW, N_W, rp_pw, cn_pw, wo_pw, pm_pw },
        { ei_wp, E_WP, N_P, rp_wp, cn_wp, wo_wp, pm_wp },
    };
    for (int t = 0; t < 3; ++t) {
        const int* src = csr[t].ei;
        const int* dst = csr[t].ei + csr[t].E;
        int n = csr[t].n_dst;
        int nb = cdiv(n, 1024);
        hipMemsetAsync(csr[t].cn, 0, (size_t)n * 4, stream);
        count_kernel<<<cdiv(csr[t].E, 256), 256, 0, stream>>>(dst, csr[t].cn, csr[t].E);
        block_sum_kernel<<<nb, 1024, 0, stream>>>(csr[t].cn, bsum, n);
        scan_bsums_kernel<<<1, 1024, 0, stream>>>(bsum, nb);
        block_scan_kernel<<<nb, 1024, 0, stream>>>(csr[t].cn, bsum, csr[t].rp, csr[t].wo, n);
        scatter_kernel<<<cdiv(csr[t].E, 256), 256, 0, stream>>>(src, dst, csr[t].wo, csr[t].pm, csr[t].E);
    }

    // input projections (fp32 h + fp16 mirror)
    gemm64<4><<<cdiv(N_P, 64), 256, 0, stream>>>(x_p, Wpp, bpp, h_p, h16_p, N_P, D_P);
    gemm64<4><<<cdiv(N_W, 64), 256, 0, stream>>>(x_w, Wpw, bpw, h_w, h16_w, N_W, D_W);

    for (int l = 0; l < LL; ++l) {
        int lt0 = l * 3 + 0, lt1 = l * 3 + 1, lt2 = l * 3 + 2;
        build_wcomb16<<<cdiv(512 * 64 + 256 * 64, 256), 256, 0, stream>>>(
            Wsrc, cbias, l, wtp, bp, wtw, bw);

        // fused attention dots: protein nodes (4 jobs), pathway nodes (2 jobs)
        av_multi<4><<<cdiv(N_P, 256), 256, 0, stream>>>(
            h_p, wv_s + (size_t)lt0 * 256, wv_d + (size_t)lt0 * 256,
            wv_s + (size_t)lt1 * 256, wv_d + (size_t)lt2 * 256,
            (float4*)a_pp_s, (float4*)a_pp_d, (float4*)a_pw_s, (float4*)a_wp_d, N_P);
        av_multi<2><<<cdiv(N_W, 256), 256, 0, stream>>>(
            h_w, wv_d + (size_t)lt1 * 256, wv_s + (size_t)lt2 * 256, nullptr, nullptr,
            (float4*)a_pw_d, (float4*)a_wp_s, nullptr, nullptr, N_W);

        // pp
        gat_stats_kernel<<<cdiv(N_P, 256), 256, 0, stream>>>(
            rp_pp, pm_pp, (const float4*)a_pp_s, (const float4*)a_pp_d, (float4*)al_pp, N_P);
        gat_msg_kernel<<<cdiv(N_P, 4), 256, 0, stream>>>(
            rp_pp, pm_pp, (const float4*)al_pp, h16_p, agg_p, 512, 0, N_P);
        // pw
        gat_stats_kernel<<<cdiv(N_W, 256), 256, 0, stream>>>(
            rp_pw, pm_pw, (const float4*)a_pw_s, (const float4*)a_pw_d, (float4*)al_pw, N_W);
        gat_msg_kernel<<<cdiv(N_W, 4), 256, 0, stream>>>(
            rp_pw, pm_pw, (const float4*)al_pw, h16_p, agg_w, 256, 0, N_W);
        // wp
        gat_stats_kernel<<<cdiv(N_P, 256), 256, 0, stream>>>(
            rp_wp, pm_wp, (const float4*)a_wp_s, (const float4*)a_wp_d, (float4*)al_wp, N_P);
        gat_msg_kernel<<<cdiv(N_P, 4), 256, 0, stream>>>(
            rp_wp, pm_wp, (const float4*)al_wp, h16_w, agg_p, 512, 256, N_P);

        // post-aggregation projections: MFMA fp16 with fused bias + ELU
        mfma_postagg<<<cdiv(N_P, 64), 256, 0, stream>>>(agg_p, wtp, bp, h_p, h16_p, N_P, 512);
        mfma_postagg<<<cdiv(N_W, 64), 256, 0, stream>>>(agg_w, wtw, bw, h_w, h16_w, N_W, 256);
    }

    float* out_p = (float*)d_out;
    float* out_w = out_p + (size_t)N_P * OUTD;
    av_kernel<8><<<cdiv(N_P, 256), 256, 0, stream>>>(h_p, Wpostp, bpostp, out_p, N_P);
    av_kernel<8><<<cdiv(N_W, 256), 256, 0, stream>>>(h_w, Wpostw, bpostw, out_w, N_W);
}